// Round 5
// baseline (1080.979 us; speedup 1.0000x reference)
//
#include <hip/hip_runtime.h>

// 2-layer GCN. CSR via bucketed counting sort.
// Gather aggregations are XCD-pinned feature-sliced: g1/g2 stored SLICE-MAJOR
// (g[slice][node][16 feats]); slice = blockIdx&7 -> one XCD per slice (dispatch
// round-robins XCDs), per-XCD working set 3.2MB < 4MB L2.

typedef short          s16x8 __attribute__((ext_vector_type(8)));
typedef float          f32x4 __attribute__((ext_vector_type(4)));
typedef unsigned short u16x4 __attribute__((ext_vector_type(4)));
typedef unsigned short u16x2 __attribute__((ext_vector_type(2)));

__device__ __forceinline__ float bf2f(unsigned short u) {
  union { unsigned int i; float f; } x; x.i = ((unsigned int)u) << 16; return x.f;
}
__device__ __forceinline__ unsigned short f2bf(float f) {
  union { float f; unsigned int i; } x; x.f = f;
  unsigned int r = x.i + 0x7FFFu + ((x.i >> 16) & 1u);
  return (unsigned short)(r >> 16);
}

// ---------------- CSR build (bucketed counting sort) ----------------

#define NBUCK_PAD 1024
#define BIN_CHUNK 8192

__global__ __launch_bounds__(256) void k_hist(const int* __restrict__ dst,
                                              int* __restrict__ bcnt, int E) {
  __shared__ int h[NBUCK_PAD];
  int t = threadIdx.x;
  for (int i = t; i < NBUCK_PAD; i += 256) h[i] = 0;
  __syncthreads();
  int stride = gridDim.x * 256;
  for (int e = blockIdx.x * 256 + t; e < E; e += stride) atomicAdd(&h[dst[e] >> 7], 1);
  __syncthreads();
  for (int i = t; i < NBUCK_PAD; i += 256) {
    int v = h[i];
    if (v) atomicAdd(bcnt + i, v);
  }
}

__global__ void k_bscan(const int* __restrict__ bcnt, int* __restrict__ bptr,
                        int* __restrict__ bcur, int* __restrict__ rowptr, int M, int E) {
  __shared__ int sh[NBUCK_PAD];
  int t = threadIdx.x;
  int v = bcnt[t];
  sh[t] = v; __syncthreads();
  int x = v;
  for (int off = 1; off < NBUCK_PAD; off <<= 1) {
    int y = (t >= off) ? sh[t - off] : 0;
    __syncthreads();
    x += y; sh[t] = x;
    __syncthreads();
  }
  bptr[t] = x - v;
  bcur[t] = x - v;
  if (t == NBUCK_PAD - 1) bptr[NBUCK_PAD] = x;
  if (t == 0) rowptr[M] = E;
}

__global__ __launch_bounds__(256) void k_bin(const int* __restrict__ src,
                                             const int* __restrict__ dst,
                                             int* __restrict__ bcur,
                                             unsigned int* __restrict__ binned, int E) {
  __shared__ int hist[NBUCK_PAD];
  __shared__ int base[NBUCK_PAD];
  int t = threadIdx.x;
  int e0 = blockIdx.x * BIN_CHUNK;
  int e1 = min(e0 + BIN_CHUNK, E);
  for (int i = t; i < NBUCK_PAD; i += 256) hist[i] = 0;
  __syncthreads();
  for (int e = e0 + t; e < e1; e += 256) atomicAdd(&hist[dst[e] >> 7], 1);
  __syncthreads();
  for (int i = t; i < NBUCK_PAD; i += 256) {
    int h = hist[i];
    base[i] = h ? atomicAdd(bcur + i, h) : 0;
    hist[i] = 0;
  }
  __syncthreads();
  for (int e = e0 + t; e < e1; e += 256) {
    int d = dst[e], s = src[e];
    int b = d >> 7;
    int p = base[b] + atomicAdd(&hist[b], 1);
    binned[p] = ((unsigned)(d & 127) << 17) | (unsigned)s;
  }
}

__global__ __launch_bounds__(256) void k_csr(const unsigned int* __restrict__ binned,
                                             const int* __restrict__ bptr,
                                             int* __restrict__ rowptr,
                                             float* __restrict__ dinv,
                                             int* __restrict__ col, int M) {
  __shared__ int deg[128];
  __shared__ int sc[128];
  __shared__ int cur[128];
  int b = blockIdx.x, t = threadIdx.x;
  int n0 = b << 7;
  int nn = min(128, M - n0);
  int e0 = bptr[b], e1 = bptr[b + 1];
  if (t < 128) deg[t] = 0;
  __syncthreads();
  for (int e = e0 + t; e < e1; e += 256) atomicAdd(&deg[(binned[e] >> 17) & 127], 1);
  __syncthreads();
  if (t < 128) sc[t] = deg[t];
  __syncthreads();
  for (int off = 1; off < 128; off <<= 1) {
    int y = 0;
    if (t < 128 && t >= off) y = sc[t - off];
    __syncthreads();
    if (t < 128) sc[t] += y;
    __syncthreads();
  }
  if (t < nn) {
    int excl = sc[t] - deg[t];
    rowptr[n0 + t] = e0 + excl;
    dinv[n0 + t] = rsqrtf((float)(deg[t] + 1));
    cur[t] = excl;
  }
  __syncthreads();
  for (int e = e0 + t; e < e1; e += 256) {
    unsigned v = binned[e];
    int dl = (v >> 17) & 127;
    int p = e0 + atomicAdd(&cur[dl], 1);
    col[p] = (int)(v & 0x1FFFFu);
  }
}

// ---------------- weight transpose+convert ----------------

__global__ void k_cvt_w(const float* __restrict__ W1, const float* __restrict__ W2,
                        unsigned short* __restrict__ w1t, unsigned short* __restrict__ w2t) {
  int i = blockIdx.x * 256 + threadIdx.x;
  if (i < 256 * 256) {
    int k = i >> 8, n = i & 255;
    w1t[n * 256 + k] = f2bf(W1[i]);
  } else {
    int j = i - 256 * 256;
    if (j < 256 * 128) {
      int k = j >> 7, n = j & 127;
      w2t[n * 256 + k] = f2bf(W2[j]);
    }
  }
}

// ---------------- GEMM1: g1 = dinv .* (x @ W1), slice-major out ----------------
// 512 thr = 8 waves (2 wm x 4 wn), tile 128 x 256, K=256, BK=32.
// out: G[slice][m][16], slice = n>>4 (16 slices).

__device__ __forceinline__ int swz4(int row, int kc) { return kc ^ ((row & 3) << 3); }

__global__ __launch_bounds__(512) void k_gemm1(
    const float* __restrict__ X, const unsigned short* __restrict__ Bt,
    const float* __restrict__ dinv, unsigned short* __restrict__ G, int M) {
  const int K = 256;
  __shared__ short lA[128 * 32];
  __shared__ short lB[256 * 32];
  int tid = threadIdx.x;
  int wid = tid >> 6, lane = tid & 63;
  int wm = wid >> 2, wn = wid & 3;
  int l15 = lane & 15;
  int lkg = (lane >> 4) * 8;
  int bm = blockIdx.x * 128;

  f32x4 acc[4][4] = {};

  for (int kt = 0; kt < 8; ++kt) {
    int k0 = kt * 32;
    __syncthreads();
#pragma unroll
    for (int h = 0; h < 2; ++h) {
      int cid = tid + h * 512;
      int r = cid >> 3, c4 = (cid & 7) * 4;
      int gr = bm + r;
      float4 v = {0.f, 0.f, 0.f, 0.f};
      if (gr < M) v = *(const float4*)(X + (size_t)gr * K + k0 + c4);
      u16x4 o; o[0] = f2bf(v.x); o[1] = f2bf(v.y); o[2] = f2bf(v.z); o[3] = f2bf(v.w);
      *(u16x4*)(&lA[r * 32 + swz4(r, c4)]) = o;
    }
#pragma unroll
    for (int h = 0; h < 2; ++h) {
      int cid = tid + h * 512;
      int n = cid >> 2, kc = (cid & 3) * 8;
      s16x8 v = *(const s16x8*)(Bt + (size_t)n * K + k0 + kc);
      *(s16x8*)(&lB[n * 32 + swz4(n, kc)]) = v;
    }
    __syncthreads();

    s16x8 af[4], bfr[4];
#pragma unroll
    for (int mi = 0; mi < 4; ++mi) {
      int r = wm * 64 + mi * 16 + l15;
      af[mi] = *(const s16x8*)(&lA[r * 32 + swz4(r, lkg)]);
    }
#pragma unroll
    for (int ni = 0; ni < 4; ++ni) {
      int c = wn * 64 + ni * 16 + l15;
      bfr[ni] = *(const s16x8*)(&lB[c * 32 + swz4(c, lkg)]);
    }
#pragma unroll
    for (int mi = 0; mi < 4; ++mi)
#pragma unroll
      for (int ni = 0; ni < 4; ++ni)
        acc[mi][ni] = __builtin_amdgcn_mfma_f32_16x16x32_bf16(af[mi], bfr[ni], acc[mi][ni], 0, 0, 0);
  }

#pragma unroll
  for (int mi = 0; mi < 4; ++mi) {
    int mrow0 = bm + wm * 64 + mi * 16 + (lane >> 4) * 4;
#pragma unroll
    for (int j = 0; j < 4; ++j) {
      int m = mrow0 + j;
      if (m < M) {
        float dv = dinv[m];
#pragma unroll
        for (int ni = 0; ni < 4; ++ni) {
          int slice = wn * 4 + ni;                          // n>>4
          G[(size_t)slice * M * 16 + (size_t)m * 16 + l15] = f2bf(acc[mi][ni][j] * dv);
        }
      }
    }
  }
}

// ---------------- sliced agg over 256 feats (16 slices, 2 phases) ----------------
// G slice-major [16][M][16]. H row-major [M][256] (gemm2 input).
// blockIdx = phase*(8*nb) + chunk*8 + slice8; slice = phase*8+slice8 -> XCD slice8.
// Block = 4 waves; wave handles 16 nodes; 8 lanes/edge (u16x2 each).

__global__ __launch_bounds__(256) void k_agg256s(
    const unsigned short* __restrict__ G, const int* __restrict__ rowptr,
    const int* __restrict__ col, const float* __restrict__ dinv,
    const float* __restrict__ bias, unsigned short* __restrict__ H,
    int M, int nb) {
  int b = blockIdx.x;
  int phase = b / (8 * nb);
  int rem = b - phase * (8 * nb);
  int chunk = rem >> 3;
  int slice = phase * 8 + (b & 7);
  int tid = threadIdx.x;
  int w = tid >> 6, lane = tid & 63;
  int fl = lane & 7;                 // feature pair within slice
  int eg = lane >> 3;                // edge within group of 8
  const unsigned short* Gs = G + (size_t)slice * M * 16;
  int fo = fl * 2;
  float bb0 = bias[slice * 16 + fo];
  float bb1 = bias[slice * 16 + fo + 1];
  int v0 = chunk * 64 + w * 16;

  for (int n = 0; n < 16; ++n) {
    int v = v0 + n;
    if (v >= M) break;
    float a0 = 0.f, a1 = 0.f;
    if (eg == 0) {
      u16x2 s = *(const u16x2*)(Gs + (size_t)v * 16 + fo);
      a0 = bf2f(s[0]); a1 = bf2f(s[1]);
    }
    int jb = rowptr[v], je = rowptr[v + 1];
    int base = jb;
    for (; base + 16 <= je; base += 16) {
      int u1 = col[base + eg];
      int u2 = col[base + 8 + eg];
      u16x2 p1 = *(const u16x2*)(Gs + (size_t)u1 * 16 + fo);
      u16x2 p2 = *(const u16x2*)(Gs + (size_t)u2 * 16 + fo);
      a0 += bf2f(p1[0]) + bf2f(p2[0]);
      a1 += bf2f(p1[1]) + bf2f(p2[1]);
    }
    for (; base < je; base += 8) {
      int idx = base + eg;
      if (idx < je) {
        int u = col[idx];
        u16x2 p = *(const u16x2*)(Gs + (size_t)u * 16 + fo);
        a0 += bf2f(p[0]); a1 += bf2f(p[1]);
      }
    }
    a0 += __shfl_xor(a0, 8, 64);  a1 += __shfl_xor(a1, 8, 64);
    a0 += __shfl_xor(a0, 16, 64); a1 += __shfl_xor(a1, 16, 64);
    a0 += __shfl_xor(a0, 32, 64); a1 += __shfl_xor(a1, 32, 64);
    if (eg == 0) {
      float dv = dinv[v];
      u16x2 o;
      o[0] = f2bf(fmaxf(fmaf(dv, a0, bb0), 0.f));
      o[1] = f2bf(fmaxf(fmaf(dv, a1, bb1), 0.f));
      *(u16x2*)(H + (size_t)v * 256 + slice * 16 + fo) = o;
    }
  }
}

// ---------------- GEMM2: g2 = dinv .* (hid @ W2), slice-major out ----------------
// 512 thr = 8 waves (2 wm x 4 wn), tile 128 x 128, K=256. out: G[slice][m][16], 8 slices.

__global__ __launch_bounds__(512) void k_gemm2(
    const unsigned short* __restrict__ A, const unsigned short* __restrict__ Bt,
    const float* __restrict__ dinv, unsigned short* __restrict__ G, int M) {
  const int K = 256;
  __shared__ short lA[128 * 32];
  __shared__ short lB[128 * 32];
  int tid = threadIdx.x;
  int wid = tid >> 6, lane = tid & 63;
  int wm = wid >> 2, wn = wid & 3;
  int l15 = lane & 15;
  int lkg = (lane >> 4) * 8;
  int bm = blockIdx.x * 128;

  f32x4 acc[4][2] = {};

  for (int kt = 0; kt < 8; ++kt) {
    int k0 = kt * 32;
    __syncthreads();
    {
      int r = tid >> 2, kc = (tid & 3) * 8;
      int gr = bm + r;
      s16x8 v = {0, 0, 0, 0, 0, 0, 0, 0};
      if (gr < M) v = *(const s16x8*)(A + (size_t)gr * K + k0 + kc);
      *(s16x8*)(&lA[r * 32 + swz4(r, kc)]) = v;
    }
    {
      int n = tid >> 2, kc = (tid & 3) * 8;
      s16x8 v = *(const s16x8*)(Bt + (size_t)n * K + k0 + kc);
      *(s16x8*)(&lB[n * 32 + swz4(n, kc)]) = v;
    }
    __syncthreads();

    s16x8 af[4], bfr[2];
#pragma unroll
    for (int mi = 0; mi < 4; ++mi) {
      int r = wm * 64 + mi * 16 + l15;
      af[mi] = *(const s16x8*)(&lA[r * 32 + swz4(r, lkg)]);
    }
#pragma unroll
    for (int ni = 0; ni < 2; ++ni) {
      int c = wn * 32 + ni * 16 + l15;
      bfr[ni] = *(const s16x8*)(&lB[c * 32 + swz4(c, lkg)]);
    }
#pragma unroll
    for (int mi = 0; mi < 4; ++mi)
#pragma unroll
      for (int ni = 0; ni < 2; ++ni)
        acc[mi][ni] = __builtin_amdgcn_mfma_f32_16x16x32_bf16(af[mi], bfr[ni], acc[mi][ni], 0, 0, 0);
  }

#pragma unroll
  for (int mi = 0; mi < 4; ++mi) {
    int mrow0 = bm + wm * 64 + mi * 16 + (lane >> 4) * 4;
#pragma unroll
    for (int j = 0; j < 4; ++j) {
      int m = mrow0 + j;
      if (m < M) {
        float dv = dinv[m];
#pragma unroll
        for (int ni = 0; ni < 2; ++ni) {
          int slice = wn * 2 + ni;                          // n>>4
          G[(size_t)slice * M * 16 + (size_t)m * 16 + l15] = f2bf(acc[mi][ni][j] * dv);
        }
      }
    }
  }
}

// ---------------- sliced agg over 128 feats (8 slices, 1 phase), fp32 out ----------------

__global__ __launch_bounds__(256) void k_agg128s(
    const unsigned short* __restrict__ G, const int* __restrict__ rowptr,
    const int* __restrict__ col, const float* __restrict__ dinv,
    const float* __restrict__ bias, float* __restrict__ Out, int M) {
  int b = blockIdx.x;
  int chunk = b >> 3;
  int slice = b & 7;
  int tid = threadIdx.x;
  int w = tid >> 6, lane = tid & 63;
  int fl = lane & 7;
  int eg = lane >> 3;
  const unsigned short* Gs = G + (size_t)slice * M * 16;
  int fo = fl * 2;
  float bb0 = bias[slice * 16 + fo];
  float bb1 = bias[slice * 16 + fo + 1];
  int v0 = chunk * 64 + w * 16;

  for (int n = 0; n < 16; ++n) {
    int v = v0 + n;
    if (v >= M) break;
    float a0 = 0.f, a1 = 0.f;
    if (eg == 0) {
      u16x2 s = *(const u16x2*)(Gs + (size_t)v * 16 + fo);
      a0 = bf2f(s[0]); a1 = bf2f(s[1]);
    }
    int jb = rowptr[v], je = rowptr[v + 1];
    int base = jb;
    for (; base + 16 <= je; base += 16) {
      int u1 = col[base + eg];
      int u2 = col[base + 8 + eg];
      u16x2 p1 = *(const u16x2*)(Gs + (size_t)u1 * 16 + fo);
      u16x2 p2 = *(const u16x2*)(Gs + (size_t)u2 * 16 + fo);
      a0 += bf2f(p1[0]) + bf2f(p2[0]);
      a1 += bf2f(p1[1]) + bf2f(p2[1]);
    }
    for (; base < je; base += 8) {
      int idx = base + eg;
      if (idx < je) {
        int u = col[idx];
        u16x2 p = *(const u16x2*)(Gs + (size_t)u * 16 + fo);
        a0 += bf2f(p[0]); a1 += bf2f(p[1]);
      }
    }
    a0 += __shfl_xor(a0, 8, 64);  a1 += __shfl_xor(a1, 8, 64);
    a0 += __shfl_xor(a0, 16, 64); a1 += __shfl_xor(a1, 16, 64);
    a0 += __shfl_xor(a0, 32, 64); a1 += __shfl_xor(a1, 32, 64);
    if (eg == 0) {
      float dv = dinv[v];
      float2 r;
      r.x = fmaxf(fmaf(dv, a0, bb0), 0.f);
      r.y = fmaxf(fmaf(dv, a1, bb1), 0.f);
      *(float2*)(Out + (size_t)v * 128 + slice * 16 + fo) = r;
    }
  }
}

// ---------------- launch ----------------

extern "C" void kernel_launch(void* const* d_in, const int* in_sizes, int n_in,
                              void* d_out, int out_size, void* d_ws, size_t ws_size,
                              hipStream_t stream) {
  const float* x  = (const float*)d_in[0];
  const float* W1 = (const float*)d_in[1];
  const float* b1 = (const float*)d_in[2];
  const float* W2 = (const float*)d_in[3];
  const float* b2 = (const float*)d_in[4];
  const int*   ei = (const int*)d_in[5];

  const int D_IN = 256, D_HID = 256, D_OUT = 128;
  const int M = in_sizes[0] / D_IN;    // 100000
  const int E = in_sizes[5] / 2;       // 3200000
  const int* src = ei;
  const int* dst = ei + E;

  char* p = (char*)d_ws;
  auto alloc = [&](size_t bytes) { void* r = (void*)p; p += (bytes + 255) & ~(size_t)255; return r; };
  float* dinv = (float*)alloc((size_t)M * 4);
  int* rowptr = (int*)alloc((size_t)(M + 1) * 4);
  int* bcnt   = (int*)alloc(NBUCK_PAD * 4);
  int* bptr   = (int*)alloc((NBUCK_PAD + 1) * 4);
  int* bcur   = (int*)alloc(NBUCK_PAD * 4);
  int* colx   = (int*)alloc((size_t)E * 4);
  unsigned short* w1t = (unsigned short*)alloc((size_t)D_HID * D_IN * 2);
  unsigned short* w2t = (unsigned short*)alloc((size_t)D_OUT * D_HID * 2);
  unsigned short* g1  = (unsigned short*)alloc((size_t)M * D_HID * 2);   // slice-major [16][M][16]
  unsigned short* hid = (unsigned short*)alloc((size_t)M * D_HID * 2);   // row-major
  unsigned short* g2  = (unsigned short*)alloc((size_t)M * D_OUT * 2);   // slice-major [8][M][16]
  unsigned int* binned = (unsigned int*)g1;   // g1 written only after k_csr consumed binned

  int nbuck = (M + 127) >> 7;                     // 782
  int nbin  = (E + BIN_CHUNK - 1) / BIN_CHUNK;    // 391
  int nb    = (M + 63) / 64;                      // 1563 node-chunks per slice

  hipMemsetAsync(bcnt, 0, NBUCK_PAD * 4, stream);
  k_hist <<<256, 256, 0, stream>>>(dst, bcnt, E);
  k_bscan<<<1, NBUCK_PAD, 0, stream>>>(bcnt, bptr, bcur, rowptr, M, E);
  k_bin  <<<nbin, 256, 0, stream>>>(src, dst, bcur, binned, E);
  k_csr  <<<nbuck, 256, 0, stream>>>(binned, bptr, rowptr, dinv, colx, M);

  k_cvt_w<<<(256 * 256 + 256 * 128 + 255) / 256, 256, 0, stream>>>(W1, W2, w1t, w2t);

  k_gemm1  <<<nbuck, 512, 0, stream>>>(x, w1t, dinv, g1, M);
  k_agg256s<<<2 * 8 * nb, 256, 0, stream>>>(g1, rowptr, colx, dinv, b1, hid, M, nb);
  k_gemm2  <<<nbuck, 512, 0, stream>>>(hid, w2t, dinv, g2, M);
  k_agg128s<<<8 * nb, 256, 0, stream>>>(g2, rowptr, colx, dinv, b2, (float*)d_out, M);
}

// Round 6
// 540.339 us; speedup vs baseline: 2.0006x; 2.0006x over previous
//
#include <hip/hip_runtime.h>

// 2-layer GCN. CSR via bucketed counting sort.
// Gathers are FEATURE-HALF split into two sequential launches so the gathered
// array half (25.6MB / 12.8MB) fits aggregate L2 (32MB), keeping 16B/lane loads.

typedef short          s16x8 __attribute__((ext_vector_type(8)));
typedef float          f32x4 __attribute__((ext_vector_type(4)));
typedef unsigned short u16x8 __attribute__((ext_vector_type(8)));
typedef unsigned short u16x4 __attribute__((ext_vector_type(4)));

__device__ __forceinline__ float bf2f(unsigned short u) {
  union { unsigned int i; float f; } x; x.i = ((unsigned int)u) << 16; return x.f;
}
__device__ __forceinline__ unsigned short f2bf(float f) {
  union { float f; unsigned int i; } x; x.f = f;
  unsigned int r = x.i + 0x7FFFu + ((x.i >> 16) & 1u);
  return (unsigned short)(r >> 16);
}

// ---------------- CSR build (bucketed counting sort) ----------------

#define NBUCK_PAD 1024
#define BIN_CHUNK 4096

__global__ __launch_bounds__(256) void k_hist(const int* __restrict__ dst,
                                              int* __restrict__ bcnt, int E) {
  __shared__ int h[NBUCK_PAD];
  int t = threadIdx.x;
  for (int i = t; i < NBUCK_PAD; i += 256) h[i] = 0;
  __syncthreads();
  int n4 = E >> 2;
  int stride = gridDim.x * 256;
  const int4* d4 = (const int4*)dst;
  for (int e = blockIdx.x * 256 + t; e < n4; e += stride) {
    int4 v = d4[e];
    atomicAdd(&h[v.x >> 7], 1);
    atomicAdd(&h[v.y >> 7], 1);
    atomicAdd(&h[v.z >> 7], 1);
    atomicAdd(&h[v.w >> 7], 1);
  }
  if (blockIdx.x == 0) {
    for (int e = n4 * 4 + t; e < E; e += 256) atomicAdd(&h[dst[e] >> 7], 1);
  }
  __syncthreads();
  for (int i = t; i < NBUCK_PAD; i += 256) {
    int v = h[i];
    if (v) atomicAdd(bcnt + i, v);
  }
}

__global__ void k_bscan(const int* __restrict__ bcnt, int* __restrict__ bptr,
                        int* __restrict__ bcur, int* __restrict__ rowptr, int M, int E) {
  __shared__ int sh[NBUCK_PAD];
  int t = threadIdx.x;
  int v = bcnt[t];
  sh[t] = v; __syncthreads();
  int x = v;
  for (int off = 1; off < NBUCK_PAD; off <<= 1) {
    int y = (t >= off) ? sh[t - off] : 0;
    __syncthreads();
    x += y; sh[t] = x;
    __syncthreads();
  }
  bptr[t] = x - v;
  bcur[t] = x - v;
  if (t == NBUCK_PAD - 1) bptr[NBUCK_PAD] = x;
  if (t == 0) rowptr[M] = E;
}

__global__ __launch_bounds__(256) void k_bin(const int* __restrict__ src,
                                             const int* __restrict__ dst,
                                             int* __restrict__ bcur,
                                             unsigned int* __restrict__ binned, int E) {
  __shared__ int hist[NBUCK_PAD];
  __shared__ int base[NBUCK_PAD];
  int t = threadIdx.x;
  int e0 = blockIdx.x * BIN_CHUNK;
  int e1 = min(e0 + BIN_CHUNK, E);
  for (int i = t; i < NBUCK_PAD; i += 256) hist[i] = 0;
  __syncthreads();
  for (int e = e0 + t; e < e1; e += 256) atomicAdd(&hist[dst[e] >> 7], 1);
  __syncthreads();
  for (int i = t; i < NBUCK_PAD; i += 256) {
    int h = hist[i];
    base[i] = h ? atomicAdd(bcur + i, h) : 0;
    hist[i] = 0;
  }
  __syncthreads();
  for (int e = e0 + t; e < e1; e += 256) {
    int d = dst[e], s = src[e];
    int b = d >> 7;
    int p = base[b] + atomicAdd(&hist[b], 1);
    binned[p] = ((unsigned)(d & 127) << 17) | (unsigned)s;
  }
}

__global__ __launch_bounds__(256) void k_csr(const unsigned int* __restrict__ binned,
                                             const int* __restrict__ bptr,
                                             int* __restrict__ rowptr,
                                             float* __restrict__ dinv,
                                             int* __restrict__ col, int M) {
  __shared__ int deg[128];
  __shared__ int sc[128];
  __shared__ int cur[128];
  int b = blockIdx.x, t = threadIdx.x;
  int n0 = b << 7;
  int nn = min(128, M - n0);
  int e0 = bptr[b], e1 = bptr[b + 1];
  if (t < 128) deg[t] = 0;
  __syncthreads();
  for (int e = e0 + t; e < e1; e += 256) atomicAdd(&deg[(binned[e] >> 17) & 127], 1);
  __syncthreads();
  if (t < 128) sc[t] = deg[t];
  __syncthreads();
  for (int off = 1; off < 128; off <<= 1) {
    int y = 0;
    if (t < 128 && t >= off) y = sc[t - off];
    __syncthreads();
    if (t < 128) sc[t] += y;
    __syncthreads();
  }
  if (t < nn) {
    int excl = sc[t] - deg[t];
    rowptr[n0 + t] = e0 + excl;
    dinv[n0 + t] = rsqrtf((float)(deg[t] + 1));
    cur[t] = excl;
  }
  __syncthreads();
  for (int e = e0 + t; e < e1; e += 256) {
    unsigned v = binned[e];
    int dl = (v >> 17) & 127;
    int p = e0 + atomicAdd(&cur[dl], 1);
    col[p] = (int)(v & 0x1FFFFu);
  }
}

// ---------------- weight transpose+convert ----------------

__global__ void k_cvt_w(const float* __restrict__ W1, const float* __restrict__ W2,
                        unsigned short* __restrict__ w1t, unsigned short* __restrict__ w2t) {
  int i = blockIdx.x * 256 + threadIdx.x;
  if (i < 256 * 256) {
    int k = i >> 8, n = i & 255;
    w1t[n * 256 + k] = f2bf(W1[i]);
  } else {
    int j = i - 256 * 256;
    if (j < 256 * 128) {
      int k = j >> 7, n = j & 127;
      w2t[n * 256 + k] = f2bf(W2[j]);
    }
  }
}

// ---------------- GEMM1: g1 = dinv .* (x @ W1), half-major out [2][M][128] ----------------

__device__ __forceinline__ int swz4(int row, int kc) { return kc ^ ((row & 3) << 3); }

__global__ __launch_bounds__(512) void k_gemm1(
    const float* __restrict__ X, const unsigned short* __restrict__ Bt,
    const float* __restrict__ dinv, unsigned short* __restrict__ G, int M) {
  const int K = 256;
  __shared__ short lA[128 * 32];
  __shared__ short lB[256 * 32];
  int tid = threadIdx.x;
  int wid = tid >> 6, lane = tid & 63;
  int wm = wid >> 2, wn = wid & 3;
  int l15 = lane & 15;
  int lkg = (lane >> 4) * 8;
  int bm = blockIdx.x * 128;

  f32x4 acc[4][4] = {};

  for (int kt = 0; kt < 8; ++kt) {
    int k0 = kt * 32;
    __syncthreads();
#pragma unroll
    for (int h = 0; h < 2; ++h) {
      int cid = tid + h * 512;
      int r = cid >> 3, c4 = (cid & 7) * 4;
      int gr = bm + r;
      float4 v = {0.f, 0.f, 0.f, 0.f};
      if (gr < M) v = *(const float4*)(X + (size_t)gr * K + k0 + c4);
      u16x4 o; o[0] = f2bf(v.x); o[1] = f2bf(v.y); o[2] = f2bf(v.z); o[3] = f2bf(v.w);
      *(u16x4*)(&lA[r * 32 + swz4(r, c4)]) = o;
    }
#pragma unroll
    for (int h = 0; h < 2; ++h) {
      int cid = tid + h * 512;
      int n = cid >> 2, kc = (cid & 3) * 8;
      s16x8 v = *(const s16x8*)(Bt + (size_t)n * K + k0 + kc);
      *(s16x8*)(&lB[n * 32 + swz4(n, kc)]) = v;
    }
    __syncthreads();

    s16x8 af[4], bfr[4];
#pragma unroll
    for (int mi = 0; mi < 4; ++mi) {
      int r = wm * 64 + mi * 16 + l15;
      af[mi] = *(const s16x8*)(&lA[r * 32 + swz4(r, lkg)]);
    }
#pragma unroll
    for (int ni = 0; ni < 4; ++ni) {
      int c = wn * 64 + ni * 16 + l15;
      bfr[ni] = *(const s16x8*)(&lB[c * 32 + swz4(c, lkg)]);
    }
#pragma unroll
    for (int mi = 0; mi < 4; ++mi)
#pragma unroll
      for (int ni = 0; ni < 4; ++ni)
        acc[mi][ni] = __builtin_amdgcn_mfma_f32_16x16x32_bf16(af[mi], bfr[ni], acc[mi][ni], 0, 0, 0);
  }

  // out feature n = wn*64 + ni*16 + l15; half = wn>>1, off = (wn&1)*64 + ni*16 + l15
#pragma unroll
  for (int mi = 0; mi < 4; ++mi) {
    int mrow0 = bm + wm * 64 + mi * 16 + (lane >> 4) * 4;
#pragma unroll
    for (int j = 0; j < 4; ++j) {
      int m = mrow0 + j;
      if (m < M) {
        float dv = dinv[m];
#pragma unroll
        for (int ni = 0; ni < 4; ++ni)
          G[(size_t)(wn >> 1) * M * 128 + (size_t)m * 128 + (wn & 1) * 64 + ni * 16 + l15]
              = f2bf(acc[mi][ni][j] * dv);
      }
    }
  }
}

// ---------------- GEMM2: g2 = dinv .* (hid @ W2), half-major out [2][M][64] ----------------

__global__ __launch_bounds__(512) void k_gemm2(
    const unsigned short* __restrict__ A, const unsigned short* __restrict__ Bt,
    const float* __restrict__ dinv, unsigned short* __restrict__ G, int M) {
  const int K = 256;
  __shared__ short lA[128 * 32];
  __shared__ short lB[128 * 32];
  int tid = threadIdx.x;
  int wid = tid >> 6, lane = tid & 63;
  int wm = wid >> 2, wn = wid & 3;
  int l15 = lane & 15;
  int lkg = (lane >> 4) * 8;
  int bm = blockIdx.x * 128;

  f32x4 acc[4][2] = {};

  for (int kt = 0; kt < 8; ++kt) {
    int k0 = kt * 32;
    __syncthreads();
    {
      int r = tid >> 2, kc = (tid & 3) * 8;
      int gr = bm + r;
      s16x8 v = {0, 0, 0, 0, 0, 0, 0, 0};
      if (gr < M) v = *(const s16x8*)(A + (size_t)gr * K + k0 + kc);
      *(s16x8*)(&lA[r * 32 + swz4(r, kc)]) = v;
    }
    {
      int n = tid >> 2, kc = (tid & 3) * 8;
      s16x8 v = *(const s16x8*)(Bt + (size_t)n * K + k0 + kc);
      *(s16x8*)(&lB[n * 32 + swz4(n, kc)]) = v;
    }
    __syncthreads();

    s16x8 af[4], bfr[2];
#pragma unroll
    for (int mi = 0; mi < 4; ++mi) {
      int r = wm * 64 + mi * 16 + l15;
      af[mi] = *(const s16x8*)(&lA[r * 32 + swz4(r, lkg)]);
    }
#pragma unroll
    for (int ni = 0; ni < 2; ++ni) {
      int c = wn * 32 + ni * 16 + l15;
      bfr[ni] = *(const s16x8*)(&lB[c * 32 + swz4(c, lkg)]);
    }
#pragma unroll
    for (int mi = 0; mi < 4; ++mi)
#pragma unroll
      for (int ni = 0; ni < 2; ++ni)
        acc[mi][ni] = __builtin_amdgcn_mfma_f32_16x16x32_bf16(af[mi], bfr[ni], acc[mi][ni], 0, 0, 0);
  }

  // out feature n = wn*32 + ni*16 + l15; half = wn>>1, off = (wn&1)*32 + ni*16 + l15
#pragma unroll
  for (int mi = 0; mi < 4; ++mi) {
    int mrow0 = bm + wm * 64 + mi * 16 + (lane >> 4) * 4;
#pragma unroll
    for (int j = 0; j < 4; ++j) {
      int m = mrow0 + j;
      if (m < M) {
        float dv = dinv[m];
#pragma unroll
        for (int ni = 0; ni < 2; ++ni)
          G[(size_t)(wn >> 1) * M * 64 + (size_t)m * 64 + (wn & 1) * 32 + ni * 16 + l15]
              = f2bf(acc[mi][ni][j] * dv);
      }
    }
  }
}

// ---------------- half-gather agg, layer 1: G=[M][128] per phase -> hid [M][256] ----------------
// One wave per node; 16 lanes x 16B per edge row (256B); 4 edge slots.

__global__ __launch_bounds__(256) void k_agg256h(
    const unsigned short* __restrict__ G, const int* __restrict__ rowptr,
    const int* __restrict__ col, const float* __restrict__ dinv,
    const float* __restrict__ bias, unsigned short* __restrict__ H,
    int M, int phase) {
  int lane = threadIdx.x & 63;
  int v = (blockIdx.x << 2) + (threadIdx.x >> 6);
  if (v >= M) return;
  int slot = lane >> 4;             // 0..3
  int f8 = (lane & 15) * 8;         // feature offset within 128
  float a[8] = {};
  if (slot == 0) {
    u16x8 s = *(const u16x8*)(G + (size_t)v * 128 + f8);
#pragma unroll
    for (int i = 0; i < 8; ++i) a[i] += bf2f(s[i]);
  }
  int jb = rowptr[v], je = rowptr[v + 1];
  int j = jb;
  for (; j + 8 <= je; j += 8) {
    int u0 = col[j + slot];
    int u1 = col[j + 4 + slot];
    u16x8 p0 = *(const u16x8*)(G + (size_t)u0 * 128 + f8);
    u16x8 p1 = *(const u16x8*)(G + (size_t)u1 * 128 + f8);
#pragma unroll
    for (int i = 0; i < 8; ++i) a[i] += bf2f(p0[i]) + bf2f(p1[i]);
  }
  for (; j + 4 <= je; j += 4) {
    int u = col[j + slot];
    u16x8 p = *(const u16x8*)(G + (size_t)u * 128 + f8);
#pragma unroll
    for (int i = 0; i < 8; ++i) a[i] += bf2f(p[i]);
  }
  int rem = je - j;
  if (slot < rem) {
    int u = col[j + slot];
    u16x8 p = *(const u16x8*)(G + (size_t)u * 128 + f8);
#pragma unroll
    for (int i = 0; i < 8; ++i) a[i] += bf2f(p[i]);
  }
#pragma unroll
  for (int i = 0; i < 8; ++i) {
    a[i] += __shfl_xor(a[i], 16, 64);
    a[i] += __shfl_xor(a[i], 32, 64);
  }
  if (lane < 16) {
    float dv = dinv[v];
    const float* bp = bias + phase * 128 + f8;
    u16x8 o;
#pragma unroll
    for (int i = 0; i < 8; ++i) o[i] = f2bf(fmaxf(fmaf(dv, a[i], bp[i]), 0.f));
    *(u16x8*)(H + (size_t)v * 256 + phase * 128 + f8) = o;
  }
}

// ---------------- half-gather agg, layer 2: G=[M][64] per phase -> out [M][128] f32 ----------------
// One wave per node; 8 lanes x 16B per edge row (128B); 8 edge slots.

__global__ __launch_bounds__(256) void k_agg128h(
    const unsigned short* __restrict__ G, const int* __restrict__ rowptr,
    const int* __restrict__ col, const float* __restrict__ dinv,
    const float* __restrict__ bias, float* __restrict__ Out,
    int M, int phase) {
  int lane = threadIdx.x & 63;
  int v = (blockIdx.x << 2) + (threadIdx.x >> 6);
  if (v >= M) return;
  int slot = lane >> 3;             // 0..7
  int f8 = (lane & 7) * 8;          // feature offset within 64
  float a[8] = {};
  if (slot == 0) {
    u16x8 s = *(const u16x8*)(G + (size_t)v * 64 + f8);
#pragma unroll
    for (int i = 0; i < 8; ++i) a[i] += bf2f(s[i]);
  }
  int jb = rowptr[v], je = rowptr[v + 1];
  int j = jb;
  for (; j + 16 <= je; j += 16) {
    int u0 = col[j + slot];
    int u1 = col[j + 8 + slot];
    u16x8 p0 = *(const u16x8*)(G + (size_t)u0 * 64 + f8);
    u16x8 p1 = *(const u16x8*)(G + (size_t)u1 * 64 + f8);
#pragma unroll
    for (int i = 0; i < 8; ++i) a[i] += bf2f(p0[i]) + bf2f(p1[i]);
  }
  for (; j + 8 <= je; j += 8) {
    int u = col[j + slot];
    u16x8 p = *(const u16x8*)(G + (size_t)u * 64 + f8);
#pragma unroll
    for (int i = 0; i < 8; ++i) a[i] += bf2f(p[i]);
  }
  int rem = je - j;
  if (slot < rem) {
    int u = col[j + slot];
    u16x8 p = *(const u16x8*)(G + (size_t)u * 64 + f8);
#pragma unroll
    for (int i = 0; i < 8; ++i) a[i] += bf2f(p[i]);
  }
#pragma unroll
  for (int i = 0; i < 8; ++i) {
    a[i] += __shfl_xor(a[i], 8, 64);
    a[i] += __shfl_xor(a[i], 16, 64);
    a[i] += __shfl_xor(a[i], 32, 64);
  }
  if (lane < 8) {
    float dv = dinv[v];
    const float* bp = bias + phase * 64 + f8;
    float4 r0, r1;
    r0.x = fmaxf(fmaf(dv, a[0], bp[0]), 0.f);
    r0.y = fmaxf(fmaf(dv, a[1], bp[1]), 0.f);
    r0.z = fmaxf(fmaf(dv, a[2], bp[2]), 0.f);
    r0.w = fmaxf(fmaf(dv, a[3], bp[3]), 0.f);
    r1.x = fmaxf(fmaf(dv, a[4], bp[4]), 0.f);
    r1.y = fmaxf(fmaf(dv, a[5], bp[5]), 0.f);
    r1.z = fmaxf(fmaf(dv, a[6], bp[6]), 0.f);
    r1.w = fmaxf(fmaf(dv, a[7], bp[7]), 0.f);
    float* op = Out + (size_t)v * 128 + phase * 64 + f8;
    *(float4*)op = r0;
    *(float4*)(op + 4) = r1;
  }
}

// ---------------- launch ----------------

extern "C" void kernel_launch(void* const* d_in, const int* in_sizes, int n_in,
                              void* d_out, int out_size, void* d_ws, size_t ws_size,
                              hipStream_t stream) {
  const float* x  = (const float*)d_in[0];
  const float* W1 = (const float*)d_in[1];
  const float* b1 = (const float*)d_in[2];
  const float* W2 = (const float*)d_in[3];
  const float* b2 = (const float*)d_in[4];
  const int*   ei = (const int*)d_in[5];

  const int D_IN = 256, D_HID = 256, D_OUT = 128;
  const int M = in_sizes[0] / D_IN;    // 100000
  const int E = in_sizes[5] / 2;       // 3200000
  const int* src = ei;
  const int* dst = ei + E;

  char* p = (char*)d_ws;
  auto alloc = [&](size_t bytes) { void* r = (void*)p; p += (bytes + 255) & ~(size_t)255; return r; };
  float* dinv = (float*)alloc((size_t)M * 4);
  int* rowptr = (int*)alloc((size_t)(M + 1) * 4);
  int* bcnt   = (int*)alloc(NBUCK_PAD * 4);
  int* bptr   = (int*)alloc((NBUCK_PAD + 1) * 4);
  int* bcur   = (int*)alloc(NBUCK_PAD * 4);
  int* colx   = (int*)alloc((size_t)E * 4);
  unsigned short* w1t = (unsigned short*)alloc((size_t)D_HID * D_IN * 2);
  unsigned short* w2t = (unsigned short*)alloc((size_t)D_OUT * D_HID * 2);
  unsigned short* g1  = (unsigned short*)alloc((size_t)M * D_HID * 2);   // [2][M][128]
  unsigned short* hid = (unsigned short*)alloc((size_t)M * D_HID * 2);   // row-major [M][256]
  unsigned short* g2  = (unsigned short*)alloc((size_t)M * D_OUT * 2);   // [2][M][64]
  unsigned int* binned = (unsigned int*)g1;   // g1 written only after k_csr consumed binned

  int nbuck = (M + 127) >> 7;                     // 782
  int nbin  = (E + BIN_CHUNK - 1) / BIN_CHUNK;    // 782
  int nb4   = (M + 3) / 4;

  hipMemsetAsync(bcnt, 0, NBUCK_PAD * 4, stream);
  k_hist <<<256, 256, 0, stream>>>(dst, bcnt, E);
  k_bscan<<<1, NBUCK_PAD, 0, stream>>>(bcnt, bptr, bcur, rowptr, M, E);
  k_bin  <<<nbin, 256, 0, stream>>>(src, dst, bcur, binned, E);
  k_csr  <<<nbuck, 256, 0, stream>>>(binned, bptr, rowptr, dinv, colx, M);

  k_cvt_w<<<(256 * 256 + 256 * 128 + 255) / 256, 256, 0, stream>>>(W1, W2, w1t, w2t);

  k_gemm1  <<<nbuck, 512, 0, stream>>>(x, w1t, dinv, g1, M);
  k_agg256h<<<nb4, 256, 0, stream>>>(g1,                      rowptr, colx, dinv, b1, hid, M, 0);
  k_agg256h<<<nb4, 256, 0, stream>>>(g1 + (size_t)M * 128,    rowptr, colx, dinv, b1, hid, M, 1);
  k_gemm2  <<<nbuck, 512, 0, stream>>>(hid, w2t, dinv, g2, M);
  k_agg128h<<<nb4, 256, 0, stream>>>(g2,                      rowptr, colx, dinv, b2, (float*)d_out, M, 0);
  k_agg128h<<<nb4, 256, 0, stream>>>(g2 + (size_t)M * 64,     rowptr, colx, dinv, b2, (float*)d_out, M, 1);
}